// Round 6
// baseline (159.803 us; speedup 1.0000x reference)
//
#include <hip/hip_runtime.h>

// Project2Dto3D: out[b,c,v] = sum over pixels hw with proj[hw]==v of feat[b,c,hw]
// B=4, C=128, H=240, W=320, V=60*36*60=129600
//
// CSR build -> fused transpose+permute to channel-last featP[j][bc] ->
// coalesced streaming gather with LDS-staged full-line output writes.
// This round: float4-vectorized global access in both big kernels.

static constexpr int HW = 240 * 320;      // 76800
static constexpr int V  = 60 * 36 * 60;   // 129600
static constexpr int B  = 4;
static constexpr int C  = 128;
static constexpr int BC = B * C;          // 512
static constexpr int NBV = (V + 255) / 256;    // 507
static constexpr int NHWT = HW / 64;      // 1200 hw-tiles
static constexpr int NBCT = BC / 64;      // 8 bc-tiles
static constexpr int VT = 16;             // voxels per gather tile
static constexpr int NVT = V / VT;        // 8100
static constexpr int SMP = BC + 1;        // padded LDS row stride (513)

typedef float f4 __attribute__((ext_vector_type(4)));

// ---------------------------------------------------------------------------
__global__ void __launch_bounds__(256) zero_kernel(int* __restrict__ cnt) {
    int i = blockIdx.x * 256 + threadIdx.x;
    if (i < V) cnt[i] = 0;
}

__global__ void __launch_bounds__(256) count_kernel(const int* __restrict__ idx,
                                                    int* __restrict__ cnt) {
    int hw = blockIdx.x * 256 + threadIdx.x;
    if (hw < HW) atomicAdd(&cnt[idx[hw]], 1);
}

__global__ void __launch_bounds__(256) blocksum_kernel(const int* __restrict__ cnt,
                                                       int* __restrict__ bsum) {
    int i = blockIdx.x * 256 + threadIdx.x;
    int v = (i < V) ? cnt[i] : 0;
#pragma unroll
    for (int d = 32; d > 0; d >>= 1) v += __shfl_down(v, d, 64);
    __shared__ int ws[4];
    if ((threadIdx.x & 63) == 0) ws[threadIdx.x >> 6] = v;
    __syncthreads();
    if (threadIdx.x == 0) bsum[blockIdx.x] = ws[0] + ws[1] + ws[2] + ws[3];
}

__global__ void __launch_bounds__(512) scan_bsum_kernel(int* __restrict__ bsum) {
    __shared__ int sm[512];
    int t = threadIdx.x;
    int v = (t < NBV) ? bsum[t] : 0;
    sm[t] = v;
    __syncthreads();
    for (int d = 1; d < 512; d <<= 1) {
        int x = (t >= d) ? sm[t - d] : 0;
        __syncthreads();
        sm[t] += x;
        __syncthreads();
    }
    if (t < NBV) bsum[t] = sm[t] - v;   // exclusive
}

// off (= cnt, in place) becomes exclusive offsets; cursor copies; off[V]=HW sentinel
__global__ void __launch_bounds__(256) scatter_off_kernel(int* __restrict__ cnt,
                                                          const int* __restrict__ bsum,
                                                          int* __restrict__ cursor) {
    int i = blockIdx.x * 256 + threadIdx.x;
    int c = (i < V) ? cnt[i] : 0;
    int lane = threadIdx.x & 63, w = threadIdx.x >> 6;
    int inc = c;
#pragma unroll
    for (int d = 1; d < 64; d <<= 1) {
        int x = __shfl_up(inc, d, 64);
        if (lane >= d) inc += x;
    }
    __shared__ int wsum[4];
    if (lane == 63) wsum[w] = inc;
    __syncthreads();
    int woff = 0;
    for (int k = 0; k < w; ++k) woff += wsum[k];
    int excl = inc - c + woff + bsum[blockIdx.x];
    if (i < V) { cnt[i] = excl; cursor[i] = excl; }
    if (i == 0) cnt[V] = HW;
}

// rank[hw] = CSR position of pixel hw (inverse permutation, coalesced write)
__global__ void __launch_bounds__(256) rank_kernel(const int* __restrict__ idx,
                                                   int* __restrict__ cursor,
                                                   int* __restrict__ rank) {
    int hw = blockIdx.x * 256 + threadIdx.x;
    if (hw < HW) {
        int v = idx[hw];
        rank[hw] = atomicAdd(&cursor[v], 1);
    }
}

// Fused transpose + permute: featP[rank[hw]][bc] = feat[bc][hw].
// 64x64 tile, f4 on both global sides:
//   load : f4 from feat row (4 full 64B lines per wave-instruction)
//   store: f4 chunks, 16 lanes x 16B = 256B contiguous per dst row.
__global__ void __launch_bounds__(256) transpose_perm_kernel(
        const float* __restrict__ feat, const int* __restrict__ rank,
        float* __restrict__ featP) {
    __shared__ float tile[64][65];   // [bc][hw], +1 pad
    __shared__ int rk[64];
    int hw0 = blockIdx.x * 64;
    int bc0 = blockIdx.y * 64;
    int t   = threadIdx.x;
    int cq  = t & 15;                // f4 column (load) / bc quad (store)
    int r0  = t >> 4;                // 0..15

    if (t < 64) rk[t] = rank[hw0 + t];

#pragma unroll
    for (int k = 0; k < 4; ++k) {
        int r = r0 + 16 * k;         // bc row 0..63
        f4 v = *(const f4*)(feat + (long long)(bc0 + r) * HW + hw0 + 4 * cq);
        tile[r][4 * cq + 0] = v.x;
        tile[r][4 * cq + 1] = v.y;
        tile[r][4 * cq + 2] = v.z;
        tile[r][4 * cq + 3] = v.w;
    }
    __syncthreads();

#pragma unroll
    for (int k = 0; k < 4; ++k) {
        int h = r0 + 16 * k;         // hw row 0..63 (wait: r0 is 0..15) -> use below
        // reassign roles: h index from r0, bc quad from cq
        int dst = rk[h];
        f4 v = { tile[4 * cq + 0][h], tile[4 * cq + 1][h],
                 tile[4 * cq + 2][h], tile[4 * cq + 3][h] };
        *(f4*)(featP + (long long)dst * BC + bc0 + 4 * cq) = v;
    }
}

// Gather: 128 threads, thread t owns bc quad [4t,4t+4) via f4 accumulation.
// featP rows for the tile are contiguous [off[v0], off[v0+16]) -> each read
// instruction covers 1KB contiguous. Output staged through LDS so every
// store instruction covers whole 64B lines.
__global__ void __launch_bounds__(128) gatherT_kernel(
        const float* __restrict__ featP, const int* __restrict__ off,
        float* __restrict__ out) {
    __shared__ float sm[VT][SMP];
    int v0 = blockIdx.x * VT;
    int t = threadIdx.x;             // 0..127

    f4 acc[VT];
#pragma unroll
    for (int i = 0; i < VT; ++i) acc[i] = (f4){0.f, 0.f, 0.f, 0.f};

    int jprev = off[v0];
#pragma unroll
    for (int i = 0; i < VT; ++i) {
        int j1 = off[v0 + i + 1];
        for (int j = jprev; j < j1; ++j)
            acc[i] += *(const f4*)(featP + (long long)j * BC + 4 * t);
        jprev = j1;
    }

#pragma unroll
    for (int i = 0; i < VT; ++i) {
        sm[i][4 * t + 0] = acc[i].x;
        sm[i][4 * t + 1] = acc[i].y;
        sm[i][4 * t + 2] = acc[i].z;
        sm[i][4 * t + 3] = acc[i].w;
    }
    __syncthreads();

    // Write phase: element e in [0, 512*4): bc = e>>2, vq = e&3.
    // Lane quads cover full 64B lines; 16 consecutive bc per instruction.
#pragma unroll
    for (int r = 0; r < 16; ++r) {
        int e  = r * 128 + t;
        int bc = e >> 2;
        int vq = e & 3;
        f4 val = { sm[vq * 4 + 0][bc], sm[vq * 4 + 1][bc],
                   sm[vq * 4 + 2][bc], sm[vq * 4 + 3][bc] };
        __builtin_nontemporal_store(val, (f4*)(out + (long long)bc * V + v0 + vq * 4));
    }
}

// ---------------------------------------------------------------------------
// Fallback gather (round-3 path) if workspace can't hold featP.
static constexpr int BCPT = 8;
static constexpr int NG = BC / BCPT;
static constexpr int NXCD = 8;
static constexpr int GPX = NG / NXCD;

__global__ void __launch_bounds__(256) perm_kernel(const int* __restrict__ idx,
                                                   int* __restrict__ cursor,
                                                   int* __restrict__ perm) {
    int hw = blockIdx.x * 256 + threadIdx.x;
    if (hw < HW) {
        int v = idx[hw];
        int pos = atomicAdd(&cursor[v], 1);
        perm[pos] = hw;
    }
}

__global__ void __launch_bounds__(256) gather_kernel(const float* __restrict__ feat,
                                                     const int* __restrict__ off,
                                                     const int* __restrict__ perm,
                                                     float* __restrict__ out) {
    int bid  = blockIdx.x;
    int xcd  = bid & (NXCD - 1);
    int lid  = bid >> 3;
    int gloc = lid / NBV;
    int vblk = lid - gloc * NBV;
    int g    = xcd * GPX + gloc;
    int v    = vblk * 256 + threadIdx.x;
    if (v >= V) return;
    int bc0 = g * BCPT;
    int j0 = off[v];
    int j1 = off[v + 1];
    const float* f = feat + (long long)bc0 * HW;
    float s[BCPT];
#pragma unroll
    for (int k = 0; k < BCPT; ++k) s[k] = 0.f;
    for (int j = j0; j < j1; ++j) {
        int p = perm[j];
#pragma unroll
        for (int k = 0; k < BCPT; ++k) s[k] += f[p + k * HW];
    }
    long long o = (long long)bc0 * V + v;
#pragma unroll
    for (int k = 0; k < BCPT; ++k)
        __builtin_nontemporal_store(s[k], &out[o + (long long)k * V]);
}

extern "C" void kernel_launch(void* const* d_in, const int* in_sizes, int n_in,
                              void* d_out, int out_size, void* d_ws, size_t ws_size,
                              hipStream_t stream) {
    const float* feat = (const float*)d_in[0];   // [4,128,240,320] f32
    const int*   idx  = (const int*)d_in[1];     // [240,320] int
    float*       out  = (float*)d_out;           // [4,128,129600] f32

    // workspace (ints): off[V+1] | cursor[V] | rank[HW] | bsum[512] | featP
    int* off    = (int*)d_ws;
    int* cursor = off + (V + 1);
    int* rank   = cursor + V;               // also 'perm' in fallback
    int* bsum   = rank + HW;
    size_t hdr_bytes = ((size_t)(V + 1 + V + HW + 512) * 4 + 255) & ~(size_t)255;
    float* featP = (float*)((char*)d_ws + hdr_bytes);
    size_t need = hdr_bytes + (size_t)HW * BC * sizeof(float);

    zero_kernel       <<<NBV, 256, 0, stream>>>(off);
    count_kernel      <<<(HW + 255) / 256, 256, 0, stream>>>(idx, off);
    blocksum_kernel   <<<NBV, 256, 0, stream>>>(off, bsum);
    scan_bsum_kernel  <<<1, 512, 0, stream>>>(bsum);
    scatter_off_kernel<<<NBV, 256, 0, stream>>>(off, bsum, cursor);

    if (ws_size >= need) {
        rank_kernel<<<(HW + 255) / 256, 256, 0, stream>>>(idx, cursor, rank);
        dim3 tgrid(NHWT, NBCT);
        transpose_perm_kernel<<<tgrid, 256, 0, stream>>>(feat, rank, featP);
        gatherT_kernel<<<NVT, 128, 0, stream>>>(featP, off, out);
    } else {
        perm_kernel<<<(HW + 255) / 256, 256, 0, stream>>>(idx, cursor, rank);
        gather_kernel<<<NXCD * GPX * NBV, 256, 0, stream>>>(feat, off, rank, out);
    }
}

// Round 7
// 143.128 us; speedup vs baseline: 1.1165x; 1.1165x over previous
//
#include <hip/hip_runtime.h>

// Project2Dto3D: out[b,c,v] = sum over pixels hw with proj[hw]==v of feat[b,c,hw]
// B=4, C=128, H=240, W=320, V=60*36*60=129600
//
// CSR build -> fused transpose+permute to channel-last featP[j][bc] (bf16) ->
// coalesced streaming gather (f32 accumulate) with LDS-staged full-line writes.
// bf16 intermediate halves the scratch round-trip (314->157 MB) and makes
// featP (78.6 MB) fully LLC-resident.

static constexpr int HW = 240 * 320;      // 76800
static constexpr int V  = 60 * 36 * 60;   // 129600
static constexpr int B  = 4;
static constexpr int C  = 128;
static constexpr int BC = B * C;          // 512
static constexpr int NBV = (V + 255) / 256;    // 507
static constexpr int NHWT = HW / 64;      // 1200 hw-tiles
static constexpr int NBCT = BC / 64;      // 8 bc-tiles
static constexpr int VT = 16;             // voxels per gather tile
static constexpr int NVT = V / VT;        // 8100
static constexpr int SMP = BC + 1;        // padded LDS row stride (513)

typedef float f4 __attribute__((ext_vector_type(4)));

static __device__ __forceinline__ unsigned short f2bf(float x) {
    unsigned int u = __builtin_bit_cast(unsigned int, x);
    unsigned int r = (u + 0x7FFFu + ((u >> 16) & 1u)) >> 16;   // RNE
    return (unsigned short)r;
}
static __device__ __forceinline__ float bf2f(unsigned short s) {
    unsigned int u = ((unsigned int)s) << 16;
    return __builtin_bit_cast(float, u);
}

// ---------------------------------------------------------------------------
__global__ void __launch_bounds__(256) zero_kernel(int* __restrict__ cnt) {
    int i = blockIdx.x * 256 + threadIdx.x;
    if (i < V) cnt[i] = 0;
}

__global__ void __launch_bounds__(256) count_kernel(const int* __restrict__ idx,
                                                    int* __restrict__ cnt) {
    int hw = blockIdx.x * 256 + threadIdx.x;
    if (hw < HW) atomicAdd(&cnt[idx[hw]], 1);
}

__global__ void __launch_bounds__(256) blocksum_kernel(const int* __restrict__ cnt,
                                                       int* __restrict__ bsum) {
    int i = blockIdx.x * 256 + threadIdx.x;
    int v = (i < V) ? cnt[i] : 0;
#pragma unroll
    for (int d = 32; d > 0; d >>= 1) v += __shfl_down(v, d, 64);
    __shared__ int ws[4];
    if ((threadIdx.x & 63) == 0) ws[threadIdx.x >> 6] = v;
    __syncthreads();
    if (threadIdx.x == 0) bsum[blockIdx.x] = ws[0] + ws[1] + ws[2] + ws[3];
}

__global__ void __launch_bounds__(512) scan_bsum_kernel(int* __restrict__ bsum) {
    __shared__ int sm[512];
    int t = threadIdx.x;
    int v = (t < NBV) ? bsum[t] : 0;
    sm[t] = v;
    __syncthreads();
    for (int d = 1; d < 512; d <<= 1) {
        int x = (t >= d) ? sm[t - d] : 0;
        __syncthreads();
        sm[t] += x;
        __syncthreads();
    }
    if (t < NBV) bsum[t] = sm[t] - v;   // exclusive
}

// off (= cnt, in place) becomes exclusive offsets; cursor copies; off[V]=HW sentinel
__global__ void __launch_bounds__(256) scatter_off_kernel(int* __restrict__ cnt,
                                                          const int* __restrict__ bsum,
                                                          int* __restrict__ cursor) {
    int i = blockIdx.x * 256 + threadIdx.x;
    int c = (i < V) ? cnt[i] : 0;
    int lane = threadIdx.x & 63, w = threadIdx.x >> 6;
    int inc = c;
#pragma unroll
    for (int d = 1; d < 64; d <<= 1) {
        int x = __shfl_up(inc, d, 64);
        if (lane >= d) inc += x;
    }
    __shared__ int wsum[4];
    if (lane == 63) wsum[w] = inc;
    __syncthreads();
    int woff = 0;
    for (int k = 0; k < w; ++k) woff += wsum[k];
    int excl = inc - c + woff + bsum[blockIdx.x];
    if (i < V) { cnt[i] = excl; cursor[i] = excl; }
    if (i == 0) cnt[V] = HW;
}

// rank[hw] = CSR position of pixel hw (inverse permutation, coalesced write)
__global__ void __launch_bounds__(256) rank_kernel(const int* __restrict__ idx,
                                                   int* __restrict__ cursor,
                                                   int* __restrict__ rank) {
    int hw = blockIdx.x * 256 + threadIdx.x;
    if (hw < HW) {
        int v = idx[hw];
        rank[hw] = atomicAdd(&cursor[v], 1);
    }
}

// Fused transpose + permute + f32->bf16: featP[rank[hw]][bc] = bf16(feat[bc][hw]).
// Loads: f4 (4 full 64B lines / wave-instr). Stores: uint4 = 8 bf16 channels;
// 8 lanes x 16B = 128B contiguous per dst row -> full-line writes.
__global__ void __launch_bounds__(256) transpose_perm_kernel(
        const float* __restrict__ feat, const int* __restrict__ rank,
        unsigned short* __restrict__ featP) {
    __shared__ float tile[64][65];   // [bc][hw], +1 pad
    __shared__ int rk[64];
    int hw0 = blockIdx.x * 64;
    int bc0 = blockIdx.y * 64;
    int t   = threadIdx.x;

    if (t < 64) rk[t] = rank[hw0 + t];

    {
        int cq = t & 15;             // hw quad 0..15
        int r0 = t >> 4;             // 0..15
#pragma unroll
        for (int k = 0; k < 4; ++k) {
            int r = r0 + 16 * k;     // bc row 0..63
            f4 v = *(const f4*)(feat + (long long)(bc0 + r) * HW + hw0 + 4 * cq);
            tile[r][4 * cq + 0] = v.x;
            tile[r][4 * cq + 1] = v.y;
            tile[r][4 * cq + 2] = v.z;
            tile[r][4 * cq + 3] = v.w;
        }
    }
    __syncthreads();

    {
        int q  = t & 7;              // 8-channel pack 0..7
        int h0 = t >> 3;             // 0..31
#pragma unroll
        for (int k = 0; k < 2; ++k) {
            int h = h0 + 32 * k;     // hw row 0..63
            int dst = rk[h];
            union { unsigned short us[8]; uint4 v; } p;
#pragma unroll
            for (int i = 0; i < 8; ++i)
                p.us[i] = f2bf(tile[8 * q + i][h]);
            *(uint4*)(featP + (long long)dst * BC + bc0 + 8 * q) = p.v;
        }
    }
}

// Gather: block = 16-voxel tile, 512 threads, thread t = channel bc=t.
// featP rows for the tile are contiguous [off[v0], off[v0+16)) -> each wave
// read is 128B contiguous (bf16). f32 accumulate. Output staged through LDS
// so every store instruction covers whole 64B lines.
__global__ void __launch_bounds__(512) gatherT_kernel(
        const unsigned short* __restrict__ featP, const int* __restrict__ off,
        float* __restrict__ out) {
    __shared__ float sm[VT][SMP];
    int v0 = blockIdx.x * VT;
    int t = threadIdx.x;
    float acc[VT];
    int jprev = off[v0];
#pragma unroll
    for (int i = 0; i < VT; ++i) {
        int j1 = off[v0 + i + 1];
        float a = 0.f;
        for (int j = jprev; j < j1; ++j)
            a += bf2f(featP[(long long)j * BC + t]);
        acc[i] = a;
        jprev = j1;
    }
#pragma unroll
    for (int i = 0; i < VT; ++i) sm[i][t] = acc[i];
    __syncthreads();

    // Write phase: element e in [0, 512*4): bc = e>>2, vq = e&3.
    // Lane quads cover full 64B lines.
#pragma unroll
    for (int r = 0; r < 4; ++r) {
        int e  = r * 512 + t;
        int bc = e >> 2;
        int vq = e & 3;
        f4 val = { sm[vq * 4 + 0][bc], sm[vq * 4 + 1][bc],
                   sm[vq * 4 + 2][bc], sm[vq * 4 + 3][bc] };
        __builtin_nontemporal_store(val, (f4*)(out + (long long)bc * V + v0 + vq * 4));
    }
}

// ---------------------------------------------------------------------------
// Fallback gather (round-3 path, f32 direct from feat) if workspace too small.
static constexpr int BCPT = 8;
static constexpr int NG = BC / BCPT;
static constexpr int NXCD = 8;
static constexpr int GPX = NG / NXCD;

__global__ void __launch_bounds__(256) perm_kernel(const int* __restrict__ idx,
                                                   int* __restrict__ cursor,
                                                   int* __restrict__ perm) {
    int hw = blockIdx.x * 256 + threadIdx.x;
    if (hw < HW) {
        int v = idx[hw];
        int pos = atomicAdd(&cursor[v], 1);
        perm[pos] = hw;
    }
}

__global__ void __launch_bounds__(256) gather_kernel(const float* __restrict__ feat,
                                                     const int* __restrict__ off,
                                                     const int* __restrict__ perm,
                                                     float* __restrict__ out) {
    int bid  = blockIdx.x;
    int xcd  = bid & (NXCD - 1);
    int lid  = bid >> 3;
    int gloc = lid / NBV;
    int vblk = lid - gloc * NBV;
    int g    = xcd * GPX + gloc;
    int v    = vblk * 256 + threadIdx.x;
    if (v >= V) return;
    int bc0 = g * BCPT;
    int j0 = off[v];
    int j1 = off[v + 1];
    const float* f = feat + (long long)bc0 * HW;
    float s[BCPT];
#pragma unroll
    for (int k = 0; k < BCPT; ++k) s[k] = 0.f;
    for (int j = j0; j < j1; ++j) {
        int p = perm[j];
#pragma unroll
        for (int k = 0; k < BCPT; ++k) s[k] += f[p + k * HW];
    }
    long long o = (long long)bc0 * V + v;
#pragma unroll
    for (int k = 0; k < BCPT; ++k)
        __builtin_nontemporal_store(s[k], &out[o + (long long)k * V]);
}

extern "C" void kernel_launch(void* const* d_in, const int* in_sizes, int n_in,
                              void* d_out, int out_size, void* d_ws, size_t ws_size,
                              hipStream_t stream) {
    const float* feat = (const float*)d_in[0];   // [4,128,240,320] f32
    const int*   idx  = (const int*)d_in[1];     // [240,320] int
    float*       out  = (float*)d_out;           // [4,128,129600] f32

    // workspace: off[V+1] | cursor[V] | rank[HW] | bsum[512] | featP (bf16)
    int* off    = (int*)d_ws;
    int* cursor = off + (V + 1);
    int* rank   = cursor + V;               // also 'perm' in fallback
    int* bsum   = rank + HW;
    size_t hdr_bytes = ((size_t)(V + 1 + V + HW + 512) * 4 + 255) & ~(size_t)255;
    unsigned short* featP = (unsigned short*)((char*)d_ws + hdr_bytes);
    size_t need = hdr_bytes + (size_t)HW * BC * sizeof(unsigned short);

    zero_kernel       <<<NBV, 256, 0, stream>>>(off);
    count_kernel      <<<(HW + 255) / 256, 256, 0, stream>>>(idx, off);
    blocksum_kernel   <<<NBV, 256, 0, stream>>>(off, bsum);
    scan_bsum_kernel  <<<1, 512, 0, stream>>>(bsum);
    scatter_off_kernel<<<NBV, 256, 0, stream>>>(off, bsum, cursor);

    if (ws_size >= need) {
        rank_kernel<<<(HW + 255) / 256, 256, 0, stream>>>(idx, cursor, rank);
        dim3 tgrid(NHWT, NBCT);
        transpose_perm_kernel<<<tgrid, 256, 0, stream>>>(feat, rank, featP);
        gatherT_kernel<<<NVT, 512, 0, stream>>>(featP, off, out);
    } else {
        perm_kernel<<<(HW + 255) / 256, 256, 0, stream>>>(idx, cursor, rank);
        gather_kernel<<<NXCD * GPX * NBV, 256, 0, stream>>>(feat, off, rank, out);
    }
}